// Round 23
// baseline (304.377 us; speedup 1.0000x reference)
//
#include <hip/hip_runtime.h>

typedef unsigned short ushort_t;
typedef __bf16  bf16x8 __attribute__((ext_vector_type(8)));
typedef float   f32x4  __attribute__((ext_vector_type(4)));
typedef unsigned short u16x8 __attribute__((ext_vector_type(8)));

#define MFMA16(a,b,c) __builtin_amdgcn_mfma_f32_16x16x32_bf16((a),(b),(c),0,0,0)
#define WAITVM(N) asm volatile("s_waitcnt vmcnt(" #N ")" ::: "memory")
#define BARRIER() do{ __builtin_amdgcn_s_barrier(); asm volatile("" ::: "memory"); }while(0)

static __device__ __forceinline__ ushort_t f2bf(float f){
  __bf16 h = (__bf16)f;
  return __builtin_bit_cast(ushort_t, h);
}
static __device__ __forceinline__ float bf2f(ushort_t b){
  union{unsigned u; float f;} x; x.u = ((unsigned)b)<<16; return x.f;
}
static __device__ __forceinline__ bf16x8 ldg_bf8u(const ushort_t* p){
  u16x8 r = *(const u16x8*)p;
  return __builtin_bit_cast(bf16x8, r);
}
static __device__ __forceinline__ bf16x8 lds_bf8(const ushort_t* p){
  u16x8 r = *(const u16x8*)p;
  return __builtin_bit_cast(bf16x8, r);
}
// async global->LDS, 16B per lane; lds dst must be wave-uniform base + lane*16
static __device__ __forceinline__ void gload_lds16(const ushort_t* g, ushort_t* l){
  __builtin_amdgcn_global_load_lds(
      (const __attribute__((address_space(1))) void*)g,
      (__attribute__((address_space(3))) void*)l, 16, 0, 0);
}

// ---------------------------------------------------------------- prep
// qkvT[n(768)][k(192)]
// woT[n(192)][k(256)]
// xwin: [win(2048)][row(64)][192] bf16, rows>=49 zeroed, chunk-swizzle baked
// WcT:  composed conv weights, [tap(9)][ks(6)][col(256)][sl(4)][j(8)],
//       XOR-swizzle baked; W'[tap][c][o] = sum_k Wv[c][k]*Wl[tap][k][o]
__global__ __launch_bounds__(256) void prep_kernel(
    const float* __restrict__ x,
    const float* __restrict__ Wq, const float* __restrict__ Wk,
    const float* __restrict__ Wv, const float* __restrict__ Wl,
    const float* __restrict__ Wo,
    ushort_t* __restrict__ qkvT, ushort_t* __restrict__ woT,
    ushort_t* __restrict__ xwin, ushort_t* __restrict__ WcT)
{
  int idx = blockIdx.x*256 + threadIdx.x;
  if(idx < 147456){
    int n = idx/192, kk = idx%192;
    const float* W = (n < 256) ? Wq : ((n < 512) ? Wk : Wv);
    qkvT[idx] = f2bf(W[kk*256 + (n & 255)]);
  } else if(idx < 196608){
    int t3 = idx - 147456;
    int col = t3/256, kk = t3%256;
    woT[t3] = f2bf(Wo[kk*192 + col]);
  } else if(idx < 3342336){
    int c = idx - 196608;               // xwin chunk id, 2048*1536
    int win = c/1536, t = c%1536;
    int row = t/24, cp = t%24;
    u16x8 o = {0,0,0,0,0,0,0,0};
    if(row < 49){
      int b = win>>6, rem = win&63, wy = rem>>3, wx = rem&7;
      size_t base = (size_t)b*3136 + wy*392 + wx*7;
      int sc = cp ^ (row&7);
      const float* src = x + (base + (row/7)*56 + (row%7))*192 + sc*8;
      float4 f0 = *(const float4*)src;
      float4 f1 = *(const float4*)(src+4);
      o[0]=f2bf(f0.x); o[1]=f2bf(f0.y); o[2]=f2bf(f0.z); o[3]=f2bf(f0.w);
      o[4]=f2bf(f1.x); o[5]=f2bf(f1.y); o[6]=f2bf(f1.z); o[7]=f2bf(f1.w);
    }
    *(u16x8*)&xwin[(size_t)c*8] = o;
  } else if(idx < 3784704){
    // compose: one output element per thread; lanes on o (coalesced Wl)
    int t = idx - 3342336;
    int o = t & 255;
    int tc = t >> 8;                    // 0..1727, block-uniform
    int tap = tc / 192, c = tc % 192;
    const float* wlp = Wl + (size_t)tap*65536 + o;
    const float* wvp = Wv + (size_t)c*256;
    float acc = 0.f;
    #pragma unroll 8
    for(int k=0;k<256;++k)
      acc += wvp[k] * wlp[(size_t)k*256];
    int ks = c>>5, r = c&31, grp = r>>3, j = r&7;
    int sl = grp ^ ((o>>1)&3);
    WcT[((size_t)tap*6 + ks)*8192 + o*32 + sl*8 + j] = f2bf(acc);
  }
}

// ---------------------------------------------------------------- fused qkv + attention
// block = 256 thr (4 waves) = one window x 4 heads; grid 4096 (2 blocks/window).
// R23: LDS OVERLAY -- q/k/vT reuse the xLds region (dead after the GEMM's
// last A-read; one extra __syncthreads separates read/write). LDS 76->52 KB
// -> 3 blocks/CU (12 waves/CU); VGPR 112 < 168 cap at 3 waves/SIMD.
__global__ __launch_bounds__(256,3) void qkvattn_kernel(
    const ushort_t* __restrict__ xwin, const ushort_t* __restrict__ WT,
    ushort_t* __restrict__ attnout)
{
  // elems: phase A: xLds [0,12288) = 64x192
  //        phase B (after barrier): qk w*4608 in [0,18432); vT 18432 + w*2048
  //        total 26624 elems = 52 KB
  __shared__ ushort_t lds[26624];
  ushort_t* xLds = lds;
  const int tid = threadIdx.x;
  const int w = tid>>6, l = tid&63, lr = l&15, g = l>>4;
  const int bid = blockIdx.x;
  const int win = bid>>1, head = (bid&1)*4 + w;
  const int b = win>>6, rem = win&63, wy = rem>>3, wx = rem&7;
  const size_t base = (size_t)b*3136 + wy*7*56 + wx*7;

  // ---- phase 1: pure linear DMA stage of pre-swizzled window x
  {
    const ushort_t* xsrc = xwin + (size_t)win*12288;
    #pragma unroll
    for(int r=0;r<6;++r)
      gload_lds16(xsrc + (size_t)(tid + r*256)*8,
                  xLds + (size_t)(r*256 + w*64)*8);
  }
  __syncthreads();   // drains vmcnt -> xLds valid

  ushort_t* qkBase = lds + w*4608;           // valid after 2nd barrier
  ushort_t* vT     = lds + 18432 + w*2048;
  const ushort_t* Wq_ = WT + (size_t)(head*32)*192;
  const ushort_t* Wk_ = WT + (size_t)(256 + head*32)*192;
  const ushort_t* Wv_ = WT + (size_t)(512 + head*32)*192;

  // ---- single 3-way interleaved q,k,v GEMM (shared A-fragments)
  {
    f32x4 aq[4][2], ak[4][2], av[4][2];
    #pragma unroll
    for(int mi=0;mi<4;++mi)
      #pragma unroll
      for(int nj=0;nj<2;++nj){
        f32x4 z={0.f,0.f,0.f,0.f};
        aq[mi][nj]=z; ak[mi][nj]=z; av[mi][nj]=z;
      }
    #pragma unroll
    for(int ks=0; ks<6; ++ks){
      bf16x8 af[4];
      #pragma unroll
      for(int mi=0;mi<4;++mi){
        int row = mi*16 + lr;
        af[mi] = lds_bf8(&xLds[(row*192 + ks*32 + g*8) ^ ((row&7)<<3)]);
      }
      bf16x8 bq[2], bk[2], bv[2];
      #pragma unroll
      for(int nj=0;nj<2;++nj){
        size_t off = (size_t)(nj*16+lr)*192 + ks*32 + g*8;
        bq[nj] = ldg_bf8u(Wq_ + off);
        bk[nj] = ldg_bf8u(Wk_ + off);
        bv[nj] = ldg_bf8u(Wv_ + off);
      }
      #pragma unroll
      for(int nj=0;nj<2;++nj)
        #pragma unroll
        for(int mi=0;mi<4;++mi){
          aq[mi][nj] = MFMA16(af[mi], bq[nj], aq[mi][nj]);
          ak[mi][nj] = MFMA16(af[mi], bk[nj], ak[mi][nj]);
          av[mi][nj] = MFMA16(af[mi], bv[nj], av[mi][nj]);
        }
    }
    __syncthreads();   // all waves done reading xLds; region reused for q/k/vT
    // q/k -> wave-private padded LDS [64][36]; v -> vT (wave-private only)
    #pragma unroll
    for(int mi=0;mi<4;++mi)
      #pragma unroll
      for(int nj=0;nj<2;++nj)
        #pragma unroll
        for(int i=0;i<4;++i){
          int row = mi*16 + g*4 + i, col = nj*16 + lr;
          qkBase[row*36 + col]        = f2bf(aq[mi][nj][i]);
          qkBase[2304 + row*36 + col] = f2bf(ak[mi][nj][i]);
          vT[(col*64 + row) ^ ((col&7)<<3)] = f2bf(av[mi][nj][i]);
        }
  }

  // ---- phase 3: QK^T
  f32x4 dot[4][4];
  #pragma unroll
  for(int mi=0;mi<4;++mi)
    #pragma unroll
    for(int nj=0;nj<4;++nj){ f32x4 z={0.f,0.f,0.f,0.f}; dot[mi][nj]=z; }
  bf16x8 qf[4], kf[4];
  #pragma unroll
  for(int t=0;t<4;++t){
    qf[t] = lds_bf8(&qkBase[(t*16+lr)*36 + g*8]);
    kf[t] = lds_bf8(&qkBase[2304 + (t*16+lr)*36 + g*8]);
  }
  #pragma unroll
  for(int mi=0;mi<4;++mi)
    #pragma unroll
    for(int nj=0;nj<4;++nj)
      dot[mi][nj] = MFMA16(qf[mi], kf[nj], dot[mi][nj]);

  // maxless softmax: P = exp2(S*sc), masked; no cross-lane ops.
  const float sc = 0.17677669529663687f * 1.4426950408889634f;
  ushort_t* pl = qkBase;   // P [64][64] reuses q/k region (frags in regs)
  #pragma unroll
  for(int mi=0;mi<4;++mi)
    #pragma unroll
    for(int nj=0;nj<4;++nj){
      int col = nj*16 + lr;
      #pragma unroll
      for(int i=0;i<4;++i){
        float e = (col < 49) ? exp2f(dot[mi][nj][i]*sc) : 0.f;
        int row = mi*16 + g*4 + i;
        pl[(row*64 + col) ^ ((row&7)<<3)] = f2bf(e);
      }
    }

  // PV + row-sum via P @ ones (lane-aligned with o's D-layout)
  u16x8 ones_u = {0x3f80,0x3f80,0x3f80,0x3f80,0x3f80,0x3f80,0x3f80,0x3f80};
  bf16x8 ones8 = __builtin_bit_cast(bf16x8, ones_u);
  f32x4 o[4][2], rsum[4];
  #pragma unroll
  for(int mi=0;mi<4;++mi){
    f32x4 z={0.f,0.f,0.f,0.f};
    o[mi][0]=z; o[mi][1]=z; rsum[mi]=z;
  }
  #pragma unroll
  for(int ks=0;ks<2;++ks){
    bf16x8 pa[4];
    #pragma unroll
    for(int mi=0;mi<4;++mi){
      int row = mi*16 + lr;
      pa[mi] = lds_bf8(&pl[(row*64 + ks*32 + g*8) ^ ((row&7)<<3)]);
    }
    #pragma unroll
    for(int nj=0;nj<2;++nj){
      int d = nj*16 + lr;
      bf16x8 vb = lds_bf8(&vT[(d*64 + ks*32 + g*8) ^ ((d&7)<<3)]);
      #pragma unroll
      for(int mi=0;mi<4;++mi) o[mi][nj] = MFMA16(pa[mi], vb, o[mi][nj]);
    }
    #pragma unroll
    for(int mi=0;mi<4;++mi) rsum[mi] = MFMA16(pa[mi], ones8, rsum[mi]);
  }
  #pragma unroll
  for(int mi=0;mi<4;++mi){
    #pragma unroll
    for(int i=0;i<4;++i){
      int row = mi*16 + g*4 + i;
      if(row < 49){
        size_t pix = base + (row/7)*56 + (row%7);
        float inv = 1.0f / rsum[mi][i];
        #pragma unroll
        for(int nj=0;nj<2;++nj)
          attnout[pix*256 + head*32 + nj*16 + lr] = f2bf(o[mi][nj][i] * inv);
      }
    }
  }
}

// ---------------------------------------------------------------- 3x3 conv (composed weights, A from xwin; measured ~115 us)
// local = x (*) W'  with K_total = 1728: 54 phases. A gathered from the
// window-blocked xwin via per-thread precomputed offsets. B = WcT.
__global__ __launch_bounds__(256,2) void conv_kernel(
    const ushort_t* __restrict__ xwin, const ushort_t* __restrict__ WcT,
    const float* __restrict__ b_local, ushort_t* __restrict__ local_out)
{
  __shared__ ushort_t aBuf[2][256*32];   // 2 x 16 KB
  __shared__ ushort_t bBuf[3][256*32];   // 3 x 16 KB
  const int bid = blockIdx.x;
  const int tile = (bid & 7) * 98 + (bid >> 3);   // XCD-contiguous (784 = 8*98)
  const int p0 = tile * 128;
  const int tid = threadIdx.x;
  const int l = tid&63, w=tid>>6, wm=w>>1, wn=w&1, lr=l&15, g=l>>4;

  unsigned maskbits[4];
  int pxloc[4];
  #pragma unroll
  for(int mi=0;mi<4;++mi){
    int p = p0 + wm*64 + mi*16 + lr;
    int rem = p % 3136;
    int y = rem/56, x = rem%56;
    unsigned mb = 0;
    #pragma unroll
    for(int tap=0;tap<9;++tap){
      int dy = tap/3 - 1, dx = tap%3 - 1;
      if(((unsigned)(y+dy) < 56u) && ((unsigned)(x+dx) < 56u)) mb |= (1u<<tap);
    }
    maskbits[mi] = mb;
    pxloc[mi] = wm*64 + mi*16 + lr + 64;
  }

  // one-time gather precompute for stageA: pixel -> (win,row) in xwin
  unsigned aBase[4]; int aR7[4], aWant[4];
  #pragma unroll
  for(int r=0;r<4;++r){
    int c = tid + r*256;
    int px = c>>2, sl = c&3;
    int px_abs = p0 - 64 + px;
    px_abs = min(max(px_abs, 0), 100351);
    int b2 = px_abs/3136, rem2 = px_abs%3136;
    int y2 = rem2/56, x2 = rem2%56;
    int win2 = b2*64 + (y2/7)*8 + (x2/7);
    int row2 = (y2%7)*7 + (x2%7);
    aBase[r] = (unsigned)win2*12288u + (unsigned)row2*192u;
    aR7[r]   = row2 & 7;
    aWant[r] = sl ^ ((px>>1)&3);
  }

  auto stageA = [&](int ks, ushort_t* dst){
    #pragma unroll
    for(int r=0;r<4;++r){
      int cp = (ks*4 + aWant[r]) ^ aR7[r];
      gload_lds16(xwin + aBase[r] + cp*8,
                  dst + (size_t)(r*256 + w*64)*8);
    }
  };
  auto stageB = [&](int ks, int tap, ushort_t* dst){
    const ushort_t* src = WcT + ((size_t)tap*6 + ks)*8192;
    #pragma unroll
    for(int r=0;r<4;++r){
      gload_lds16(src + (size_t)(tid + r*256)*8,
                  dst + (size_t)(r*256 + w*64)*8);
    }
  };

  f32x4 acc[4][8];
  #pragma unroll
  for(int mi=0;mi<4;++mi)
    #pragma unroll
    for(int nj=0;nj<8;++nj){ f32x4 z={0.f,0.f,0.f,0.f}; acc[mi][nj]=z; }

  auto compute = [&](int tap, const ushort_t* aL, const ushort_t* bL){
    int shift = (tap/3 - 1)*56 + (tap%3 - 1);
    bf16x8 af[4];
    #pragma unroll
    for(int mi=0;mi<4;++mi){
      int px = pxloc[mi] + shift;
      int sl = g ^ ((px>>1)&3);
      u16x8 rv = *(const u16x8*)&aL[px*32 + sl*8];
      if(!((maskbits[mi]>>tap)&1)){ u16x8 z={0,0,0,0,0,0,0,0}; rv=z; }
      af[mi] = __builtin_bit_cast(bf16x8, rv);
    }
    __builtin_amdgcn_s_setprio(1);
    #pragma unroll
    for(int nj=0;nj<8;++nj){
      int col = wn*128 + nj*16 + lr;
      int slb = g ^ ((col>>1)&3);
      bf16x8 bfr = lds_bf8(&bL[col*32 + slb*8]);
      #pragma unroll
      for(int mi=0;mi<4;++mi) acc[mi][nj] = MFMA16(af[mi], bfr, acc[mi][nj]);
    }
    __builtin_amdgcn_s_setprio(0);
  };

  stageA(0, aBuf[0]);
  stageB(0, 0, bBuf[0]);
  stageB(0, 1, bBuf[1]);

  for(int ks=0; ks<5; ++ks){
    #pragma unroll
    for(int tap=0; tap<9; ++tap){
      if(tap==1) WAITVM(8); else WAITVM(4);
      BARRIER();
      if(tap==0) stageA(ks+1, aBuf[(ks+1)&1]);
      stageB(ks + (tap+2)/9, (tap+2)%9, bBuf[(tap+2)%3]);
      compute(tap, aBuf[ks&1], bBuf[tap%3]);
    }
  }
  #pragma unroll
  for(int tap=0; tap<9; ++tap){
    if(tap==8) WAITVM(0); else WAITVM(4);
    BARRIER();
    if(tap<7) stageB(5, tap+2, bBuf[(tap+2)%3]);
    compute(tap, aBuf[1], bBuf[tap%3]);
  }

  #pragma unroll
  for(int nj=0;nj<8;++nj){
    int col = wn*128 + nj*16 + lr;
    float bb = b_local[col];
    #pragma unroll
    for(int mi=0;mi<4;++mi)
      #pragma unroll
      for(int i=0;i<4;++i){
        int p = p0 + wm*64 + mi*16 + g*4 + i;
        local_out[(size_t)p*256 + col] = f2bf(acc[mi][nj][i] + bb);
      }
  }
}

// ---------------------------------------------------------------- out proj
// out[100352,192] = (attnout+locl)[100352,256] @ Wout[256,192] + b_out
// 64px x 192col blocks, 4 waves (1m x 4n), wave 64x48; add fused in staging.
__global__ __launch_bounds__(256,4) void outproj_kernel(
    const ushort_t* __restrict__ attnout, const ushort_t* __restrict__ locl,
    const ushort_t* __restrict__ WoT, const float* __restrict__ b_out,
    float* __restrict__ out)
{
  __shared__ ushort_t aLds[64*256];   // 32 KB
  const int m0 = blockIdx.x * 64;
  const int tid = threadIdx.x;
  const int l = tid&63, w = tid>>6, lr=l&15, g=l>>4;
  #pragma unroll
  for(int r=0;r<8;++r){
    int c = tid + r*256;           // 2048 chunks = 64 rows x 32
    int row = c>>5, cc = c&31;
    size_t off = (size_t)(m0+row)*256 + cc*8;
    u16x8 a = *(const u16x8*)(attnout + off);
    u16x8 b2 = *(const u16x8*)(locl + off);
    u16x8 o;
    #pragma unroll
    for(int j=0;j<8;++j) o[j] = f2bf(bf2f(a[j]) + bf2f(b2[j]));
    *(u16x8*)&aLds[(row*256 + cc*8) ^ ((row&7)<<3)] = o;
  }
  __syncthreads();

  const ushort_t* Wbase = WoT + (size_t)(w*48)*256;
  f32x4 acc[4][3];
  #pragma unroll
  for(int mi=0;mi<4;++mi)
    #pragma unroll
    for(int nj=0;nj<3;++nj){ f32x4 z={0.f,0.f,0.f,0.f}; acc[mi][nj]=z; }

  #pragma unroll
  for(int ks=0;ks<8;++ks){
    bf16x8 bfr[3];
    #pragma unroll
    for(int nj=0;nj<3;++nj)
      bfr[nj] = ldg_bf8u(Wbase + (size_t)(nj*16+lr)*256 + ks*32 + g*8);
    bf16x8 af[4];
    #pragma unroll
    for(int mi=0;mi<4;++mi){
      int row = mi*16 + lr;
      af[mi] = lds_bf8(&aLds[(row*256 + ks*32 + g*8) ^ ((row&7)<<3)]);
    }
    #pragma unroll
    for(int nj=0;nj<3;++nj)
      #pragma unroll
      for(int mi=0;mi<4;++mi) acc[mi][nj] = MFMA16(af[mi], bfr[nj], acc[mi][nj]);
  }
  #pragma unroll
  for(int nj=0;nj<3;++nj){
    int col = w*48 + nj*16 + lr;
    float bb = b_out[col];
    #pragma unroll
    for(int mi=0;mi<4;++mi)
      #pragma unroll
      for(int i=0;i<4;++i){
        int row = mi*16 + g*4 + i;
        out[(size_t)(m0+row)*192 + col] = acc[mi][nj][i] + bb;
      }
  }
}

extern "C" void kernel_launch(void* const* d_in, const int* in_sizes, int n_in,
                              void* d_out, int out_size, void* d_ws, size_t ws_size,
                              hipStream_t stream)
{
  const float* x  = (const float*)d_in[0];
  const float* Wq = (const float*)d_in[1];
  const float* Wk = (const float*)d_in[2];
  const float* Wv = (const float*)d_in[3];
  const float* Wl = (const float*)d_in[4];
  const float* bl = (const float*)d_in[5];
  const float* Wo = (const float*)d_in[6];
  const float* bo = (const float*)d_in[7];
  float* out = (float*)d_out;
  char* ws = (char*)d_ws;
  ushort_t* attnout = (ushort_t*)(ws);                 // 51.4 MB
  ushort_t* xwin    = (ushort_t*)(ws + 51380224);      // 50.3 MB
  ushort_t* locl    = (ushort_t*)(ws + 205520896);     // 51.4 MB
  ushort_t* qkvT    = (ushort_t*)(ws + 256901120);
  ushort_t* WcT     = (ushort_t*)(ws + 257196032);     // 884 KB
  ushort_t* woT     = (ushort_t*)(ws + 258375680);

  prep_kernel<<<14784, 256, 0, stream>>>(x, Wq, Wk, Wv, Wl, Wo,
                                         qkvT, woT, xwin, WcT);
  qkvattn_kernel<<<4096, 256, 0, stream>>>(xwin, qkvT, attnout);
  conv_kernel<<<784, 256, 0, stream>>>(xwin, WcT, bl, locl);
  outproj_kernel<<<1568, 256, 0, stream>>>(attnout, locl, woT, bo, out);
}

// Round 24
// 301.780 us; speedup vs baseline: 1.0086x; 1.0086x over previous
//
#include <hip/hip_runtime.h>

typedef unsigned short ushort_t;
typedef __bf16  bf16x8 __attribute__((ext_vector_type(8)));
typedef float   f32x4  __attribute__((ext_vector_type(4)));
typedef unsigned short u16x8 __attribute__((ext_vector_type(8)));

#define MFMA16(a,b,c) __builtin_amdgcn_mfma_f32_16x16x32_bf16((a),(b),(c),0,0,0)
#define WAITVM(N) asm volatile("s_waitcnt vmcnt(" #N ")" ::: "memory")
#define BARRIER() do{ __builtin_amdgcn_s_barrier(); asm volatile("" ::: "memory"); }while(0)

static __device__ __forceinline__ ushort_t f2bf(float f){
  __bf16 h = (__bf16)f;
  return __builtin_bit_cast(ushort_t, h);
}
static __device__ __forceinline__ float bf2f(ushort_t b){
  union{unsigned u; float f;} x; x.u = ((unsigned)b)<<16; return x.f;
}
static __device__ __forceinline__ bf16x8 ldg_bf8u(const ushort_t* p){
  u16x8 r = *(const u16x8*)p;
  return __builtin_bit_cast(bf16x8, r);
}
static __device__ __forceinline__ bf16x8 lds_bf8(const ushort_t* p){
  u16x8 r = *(const u16x8*)p;
  return __builtin_bit_cast(bf16x8, r);
}
// async global->LDS, 16B per lane; lds dst must be wave-uniform base + lane*16
static __device__ __forceinline__ void gload_lds16(const ushort_t* g, ushort_t* l){
  __builtin_amdgcn_global_load_lds(
      (const __attribute__((address_space(1))) void*)g,
      (__attribute__((address_space(3))) void*)l, 16, 0, 0);
}

// ---------------------------------------------------------------- prep
// qkvT[n(768)][k(192)]
// woT[n(192)][k(256)]
// xwin: [win(2048)][row(64)][192] bf16, rows>=49 zeroed, chunk-swizzle baked
// WcT:  composed conv weights, [tap(9)][ks(6)][col(256)][sl(4)][j(8)],
//       XOR-swizzle baked; W'[tap][c][o] = sum_k Wv[c][k]*Wl[tap][k][o]
__global__ __launch_bounds__(256) void prep_kernel(
    const float* __restrict__ x,
    const float* __restrict__ Wq, const float* __restrict__ Wk,
    const float* __restrict__ Wv, const float* __restrict__ Wl,
    const float* __restrict__ Wo,
    ushort_t* __restrict__ qkvT, ushort_t* __restrict__ woT,
    ushort_t* __restrict__ xwin, ushort_t* __restrict__ WcT)
{
  int idx = blockIdx.x*256 + threadIdx.x;
  if(idx < 147456){
    int n = idx/192, kk = idx%192;
    const float* W = (n < 256) ? Wq : ((n < 512) ? Wk : Wv);
    qkvT[idx] = f2bf(W[kk*256 + (n & 255)]);
  } else if(idx < 196608){
    int t3 = idx - 147456;
    int col = t3/256, kk = t3%256;
    woT[t3] = f2bf(Wo[kk*192 + col]);
  } else if(idx < 3342336){
    int c = idx - 196608;               // xwin chunk id, 2048*1536
    int win = c/1536, t = c%1536;
    int row = t/24, cp = t%24;
    u16x8 o = {0,0,0,0,0,0,0,0};
    if(row < 49){
      int b = win>>6, rem = win&63, wy = rem>>3, wx = rem&7;
      size_t base = (size_t)b*3136 + wy*392 + wx*7;
      int sc = cp ^ (row&7);
      const float* src = x + (base + (row/7)*56 + (row%7))*192 + sc*8;
      float4 f0 = *(const float4*)src;
      float4 f1 = *(const float4*)(src+4);
      o[0]=f2bf(f0.x); o[1]=f2bf(f0.y); o[2]=f2bf(f0.z); o[3]=f2bf(f0.w);
      o[4]=f2bf(f1.x); o[5]=f2bf(f1.y); o[6]=f2bf(f1.z); o[7]=f2bf(f1.w);
    }
    *(u16x8*)&xwin[(size_t)c*8] = o;
  } else if(idx < 3784704){
    // compose: one output element per thread; lanes on o (coalesced Wl)
    int t = idx - 3342336;
    int o = t & 255;
    int tc = t >> 8;                    // 0..1727, block-uniform
    int tap = tc / 192, c = tc % 192;
    const float* wlp = Wl + (size_t)tap*65536 + o;
    const float* wvp = Wv + (size_t)c*256;
    float acc = 0.f;
    #pragma unroll 8
    for(int k=0;k<256;++k)
      acc += wvp[k] * wlp[(size_t)k*256];
    int ks = c>>5, r = c&31, grp = r>>3, j = r&7;
    int sl = grp ^ ((o>>1)&3);
    WcT[((size_t)tap*6 + ks)*8192 + o*32 + sl*8 + j] = f2bf(acc);
  }
}

// ---------------------------------------------------------------- fused qkv + attention
// block = 256 thr (4 waves) = one window x 4 heads; grid 4096 (2 blocks/window).
// LDS OVERLAY: q/k/vT reuse the xLds region (dead after the GEMM's last
// A-read; extra __syncthreads separates read/write). LDS 52 KB.
// R24: __launch_bounds__(256,2) -- NOT (256,3): r23's (256,3) forced an
// 84-reg allocation and spilled the 3 accumulator sets (+64 MB scratch
// writes). With the natural 112 VGPR, HW occupancy still reaches 3 blocks/CU
// (LDS 3x52=156<=160 KB; VGPR 3x112=336<=512 per SIMD).
__global__ __launch_bounds__(256,2) void qkvattn_kernel(
    const ushort_t* __restrict__ xwin, const ushort_t* __restrict__ WT,
    ushort_t* __restrict__ attnout)
{
  // elems: phase A: xLds [0,12288) = 64x192
  //        phase B (after barrier): qk w*4608 in [0,18432); vT 18432 + w*2048
  //        total 26624 elems = 52 KB
  __shared__ ushort_t lds[26624];
  ushort_t* xLds = lds;
  const int tid = threadIdx.x;
  const int w = tid>>6, l = tid&63, lr = l&15, g = l>>4;
  const int bid = blockIdx.x;
  const int win = bid>>1, head = (bid&1)*4 + w;
  const int b = win>>6, rem = win&63, wy = rem>>3, wx = rem&7;
  const size_t base = (size_t)b*3136 + wy*7*56 + wx*7;

  // ---- phase 1: pure linear DMA stage of pre-swizzled window x
  {
    const ushort_t* xsrc = xwin + (size_t)win*12288;
    #pragma unroll
    for(int r=0;r<6;++r)
      gload_lds16(xsrc + (size_t)(tid + r*256)*8,
                  xLds + (size_t)(r*256 + w*64)*8);
  }
  __syncthreads();   // drains vmcnt -> xLds valid

  ushort_t* qkBase = lds + w*4608;           // valid after 2nd barrier
  ushort_t* vT     = lds + 18432 + w*2048;
  const ushort_t* Wq_ = WT + (size_t)(head*32)*192;
  const ushort_t* Wk_ = WT + (size_t)(256 + head*32)*192;
  const ushort_t* Wv_ = WT + (size_t)(512 + head*32)*192;

  // ---- single 3-way interleaved q,k,v GEMM (shared A-fragments)
  {
    f32x4 aq[4][2], ak[4][2], av[4][2];
    #pragma unroll
    for(int mi=0;mi<4;++mi)
      #pragma unroll
      for(int nj=0;nj<2;++nj){
        f32x4 z={0.f,0.f,0.f,0.f};
        aq[mi][nj]=z; ak[mi][nj]=z; av[mi][nj]=z;
      }
    #pragma unroll
    for(int ks=0; ks<6; ++ks){
      bf16x8 af[4];
      #pragma unroll
      for(int mi=0;mi<4;++mi){
        int row = mi*16 + lr;
        af[mi] = lds_bf8(&xLds[(row*192 + ks*32 + g*8) ^ ((row&7)<<3)]);
      }
      bf16x8 bq[2], bk[2], bv[2];
      #pragma unroll
      for(int nj=0;nj<2;++nj){
        size_t off = (size_t)(nj*16+lr)*192 + ks*32 + g*8;
        bq[nj] = ldg_bf8u(Wq_ + off);
        bk[nj] = ldg_bf8u(Wk_ + off);
        bv[nj] = ldg_bf8u(Wv_ + off);
      }
      #pragma unroll
      for(int nj=0;nj<2;++nj)
        #pragma unroll
        for(int mi=0;mi<4;++mi){
          aq[mi][nj] = MFMA16(af[mi], bq[nj], aq[mi][nj]);
          ak[mi][nj] = MFMA16(af[mi], bk[nj], ak[mi][nj]);
          av[mi][nj] = MFMA16(af[mi], bv[nj], av[mi][nj]);
        }
    }
    __syncthreads();   // all waves done reading xLds; region reused for q/k/vT
    // q/k -> wave-private padded LDS [64][36]; v -> vT (wave-private only)
    #pragma unroll
    for(int mi=0;mi<4;++mi)
      #pragma unroll
      for(int nj=0;nj<2;++nj)
        #pragma unroll
        for(int i=0;i<4;++i){
          int row = mi*16 + g*4 + i, col = nj*16 + lr;
          qkBase[row*36 + col]        = f2bf(aq[mi][nj][i]);
          qkBase[2304 + row*36 + col] = f2bf(ak[mi][nj][i]);
          vT[(col*64 + row) ^ ((col&7)<<3)] = f2bf(av[mi][nj][i]);
        }
  }

  // ---- phase 3: QK^T
  f32x4 dot[4][4];
  #pragma unroll
  for(int mi=0;mi<4;++mi)
    #pragma unroll
    for(int nj=0;nj<4;++nj){ f32x4 z={0.f,0.f,0.f,0.f}; dot[mi][nj]=z; }
  bf16x8 qf[4], kf[4];
  #pragma unroll
  for(int t=0;t<4;++t){
    qf[t] = lds_bf8(&qkBase[(t*16+lr)*36 + g*8]);
    kf[t] = lds_bf8(&qkBase[2304 + (t*16+lr)*36 + g*8]);
  }
  #pragma unroll
  for(int mi=0;mi<4;++mi)
    #pragma unroll
    for(int nj=0;nj<4;++nj)
      dot[mi][nj] = MFMA16(qf[mi], kf[nj], dot[mi][nj]);

  // maxless softmax: P = exp2(S*sc), masked; no cross-lane ops.
  const float sc = 0.17677669529663687f * 1.4426950408889634f;
  ushort_t* pl = qkBase;   // P [64][64] reuses q/k region (frags in regs)
  #pragma unroll
  for(int mi=0;mi<4;++mi)
    #pragma unroll
    for(int nj=0;nj<4;++nj){
      int col = nj*16 + lr;
      #pragma unroll
      for(int i=0;i<4;++i){
        float e = (col < 49) ? exp2f(dot[mi][nj][i]*sc) : 0.f;
        int row = mi*16 + g*4 + i;
        pl[(row*64 + col) ^ ((row&7)<<3)] = f2bf(e);
      }
    }

  // PV + row-sum via P @ ones (lane-aligned with o's D-layout)
  u16x8 ones_u = {0x3f80,0x3f80,0x3f80,0x3f80,0x3f80,0x3f80,0x3f80,0x3f80};
  bf16x8 ones8 = __builtin_bit_cast(bf16x8, ones_u);
  f32x4 o[4][2], rsum[4];
  #pragma unroll
  for(int mi=0;mi<4;++mi){
    f32x4 z={0.f,0.f,0.f,0.f};
    o[mi][0]=z; o[mi][1]=z; rsum[mi]=z;
  }
  #pragma unroll
  for(int ks=0;ks<2;++ks){
    bf16x8 pa[4];
    #pragma unroll
    for(int mi=0;mi<4;++mi){
      int row = mi*16 + lr;
      pa[mi] = lds_bf8(&pl[(row*64 + ks*32 + g*8) ^ ((row&7)<<3)]);
    }
    #pragma unroll
    for(int nj=0;nj<2;++nj){
      int d = nj*16 + lr;
      bf16x8 vb = lds_bf8(&vT[(d*64 + ks*32 + g*8) ^ ((d&7)<<3)]);
      #pragma unroll
      for(int mi=0;mi<4;++mi) o[mi][nj] = MFMA16(pa[mi], vb, o[mi][nj]);
    }
    #pragma unroll
    for(int mi=0;mi<4;++mi) rsum[mi] = MFMA16(pa[mi], ones8, rsum[mi]);
  }
  #pragma unroll
  for(int mi=0;mi<4;++mi){
    #pragma unroll
    for(int i=0;i<4;++i){
      int row = mi*16 + g*4 + i;
      if(row < 49){
        size_t pix = base + (row/7)*56 + (row%7);
        float inv = 1.0f / rsum[mi][i];
        #pragma unroll
        for(int nj=0;nj<2;++nj)
          attnout[pix*256 + head*32 + nj*16 + lr] = f2bf(o[mi][nj][i] * inv);
      }
    }
  }
}

// ---------------------------------------------------------------- 3x3 conv (composed weights, A from xwin; measured ~115 us)
// local = x (*) W'  with K_total = 1728: 54 phases. A gathered from the
// window-blocked xwin via per-thread precomputed offsets. B = WcT.
__global__ __launch_bounds__(256,2) void conv_kernel(
    const ushort_t* __restrict__ xwin, const ushort_t* __restrict__ WcT,
    const float* __restrict__ b_local, ushort_t* __restrict__ local_out)
{
  __shared__ ushort_t aBuf[2][256*32];   // 2 x 16 KB
  __shared__ ushort_t bBuf[3][256*32];   // 3 x 16 KB
  const int bid = blockIdx.x;
  const int tile = (bid & 7) * 98 + (bid >> 3);   // XCD-contiguous (784 = 8*98)
  const int p0 = tile * 128;
  const int tid = threadIdx.x;
  const int l = tid&63, w=tid>>6, wm=w>>1, wn=w&1, lr=l&15, g=l>>4;

  unsigned maskbits[4];
  int pxloc[4];
  #pragma unroll
  for(int mi=0;mi<4;++mi){
    int p = p0 + wm*64 + mi*16 + lr;
    int rem = p % 3136;
    int y = rem/56, x = rem%56;
    unsigned mb = 0;
    #pragma unroll
    for(int tap=0;tap<9;++tap){
      int dy = tap/3 - 1, dx = tap%3 - 1;
      if(((unsigned)(y+dy) < 56u) && ((unsigned)(x+dx) < 56u)) mb |= (1u<<tap);
    }
    maskbits[mi] = mb;
    pxloc[mi] = wm*64 + mi*16 + lr + 64;
  }

  // one-time gather precompute for stageA: pixel -> (win,row) in xwin
  unsigned aBase[4]; int aR7[4], aWant[4];
  #pragma unroll
  for(int r=0;r<4;++r){
    int c = tid + r*256;
    int px = c>>2, sl = c&3;
    int px_abs = p0 - 64 + px;
    px_abs = min(max(px_abs, 0), 100351);
    int b2 = px_abs/3136, rem2 = px_abs%3136;
    int y2 = rem2/56, x2 = rem2%56;
    int win2 = b2*64 + (y2/7)*8 + (x2/7);
    int row2 = (y2%7)*7 + (x2%7);
    aBase[r] = (unsigned)win2*12288u + (unsigned)row2*192u;
    aR7[r]   = row2 & 7;
    aWant[r] = sl ^ ((px>>1)&3);
  }

  auto stageA = [&](int ks, ushort_t* dst){
    #pragma unroll
    for(int r=0;r<4;++r){
      int cp = (ks*4 + aWant[r]) ^ aR7[r];
      gload_lds16(xwin + aBase[r] + cp*8,
                  dst + (size_t)(r*256 + w*64)*8);
    }
  };
  auto stageB = [&](int ks, int tap, ushort_t* dst){
    const ushort_t* src = WcT + ((size_t)tap*6 + ks)*8192;
    #pragma unroll
    for(int r=0;r<4;++r){
      gload_lds16(src + (size_t)(tid + r*256)*8,
                  dst + (size_t)(r*256 + w*64)*8);
    }
  };

  f32x4 acc[4][8];
  #pragma unroll
  for(int mi=0;mi<4;++mi)
    #pragma unroll
    for(int nj=0;nj<8;++nj){ f32x4 z={0.f,0.f,0.f,0.f}; acc[mi][nj]=z; }

  auto compute = [&](int tap, const ushort_t* aL, const ushort_t* bL){
    int shift = (tap/3 - 1)*56 + (tap%3 - 1);
    bf16x8 af[4];
    #pragma unroll
    for(int mi=0;mi<4;++mi){
      int px = pxloc[mi] + shift;
      int sl = g ^ ((px>>1)&3);
      u16x8 rv = *(const u16x8*)&aL[px*32 + sl*8];
      if(!((maskbits[mi]>>tap)&1)){ u16x8 z={0,0,0,0,0,0,0,0}; rv=z; }
      af[mi] = __builtin_bit_cast(bf16x8, rv);
    }
    __builtin_amdgcn_s_setprio(1);
    #pragma unroll
    for(int nj=0;nj<8;++nj){
      int col = wn*128 + nj*16 + lr;
      int slb = g ^ ((col>>1)&3);
      bf16x8 bfr = lds_bf8(&bL[col*32 + slb*8]);
      #pragma unroll
      for(int mi=0;mi<4;++mi) acc[mi][nj] = MFMA16(af[mi], bfr, acc[mi][nj]);
    }
    __builtin_amdgcn_s_setprio(0);
  };

  stageA(0, aBuf[0]);
  stageB(0, 0, bBuf[0]);
  stageB(0, 1, bBuf[1]);

  for(int ks=0; ks<5; ++ks){
    #pragma unroll
    for(int tap=0; tap<9; ++tap){
      if(tap==1) WAITVM(8); else WAITVM(4);
      BARRIER();
      if(tap==0) stageA(ks+1, aBuf[(ks+1)&1]);
      stageB(ks + (tap+2)/9, (tap+2)%9, bBuf[(tap+2)%3]);
      compute(tap, aBuf[ks&1], bBuf[tap%3]);
    }
  }
  #pragma unroll
  for(int tap=0; tap<9; ++tap){
    if(tap==8) WAITVM(0); else WAITVM(4);
    BARRIER();
    if(tap<7) stageB(5, tap+2, bBuf[(tap+2)%3]);
    compute(tap, aBuf[1], bBuf[tap%3]);
  }

  #pragma unroll
  for(int nj=0;nj<8;++nj){
    int col = wn*128 + nj*16 + lr;
    float bb = b_local[col];
    #pragma unroll
    for(int mi=0;mi<4;++mi)
      #pragma unroll
      for(int i=0;i<4;++i){
        int p = p0 + wm*64 + mi*16 + g*4 + i;
        local_out[(size_t)p*256 + col] = f2bf(acc[mi][nj][i] + bb);
      }
  }
}

// ---------------------------------------------------------------- out proj
// out[100352,192] = (attnout+locl)[100352,256] @ Wout[256,192] + b_out
// 64px x 192col blocks, 4 waves (1m x 4n), wave 64x48; add fused in staging.
__global__ __launch_bounds__(256,4) void outproj_kernel(
    const ushort_t* __restrict__ attnout, const ushort_t* __restrict__ locl,
    const ushort_t* __restrict__ WoT, const float* __restrict__ b_out,
    float* __restrict__ out)
{
  __shared__ ushort_t aLds[64*256];   // 32 KB
  const int m0 = blockIdx.x * 64;
  const int tid = threadIdx.x;
  const int l = tid&63, w = tid>>6, lr=l&15, g=l>>4;
  #pragma unroll
  for(int r=0;r<8;++r){
    int c = tid + r*256;           // 2048 chunks = 64 rows x 32
    int row = c>>5, cc = c&31;
    size_t off = (size_t)(m0+row)*256 + cc*8;
    u16x8 a = *(const u16x8*)(attnout + off);
    u16x8 b2 = *(const u16x8*)(locl + off);
    u16x8 o;
    #pragma unroll
    for(int j=0;j<8;++j) o[j] = f2bf(bf2f(a[j]) + bf2f(b2[j]));
    *(u16x8*)&aLds[(row*256 + cc*8) ^ ((row&7)<<3)] = o;
  }
  __syncthreads();

  const ushort_t* Wbase = WoT + (size_t)(w*48)*256;
  f32x4 acc[4][3];
  #pragma unroll
  for(int mi=0;mi<4;++mi)
    #pragma unroll
    for(int nj=0;nj<3;++nj){ f32x4 z={0.f,0.f,0.f,0.f}; acc[mi][nj]=z; }

  #pragma unroll
  for(int ks=0;ks<8;++ks){
    bf16x8 bfr[3];
    #pragma unroll
    for(int nj=0;nj<3;++nj)
      bfr[nj] = ldg_bf8u(Wbase + (size_t)(nj*16+lr)*256 + ks*32 + g*8);
    bf16x8 af[4];
    #pragma unroll
    for(int mi=0;mi<4;++mi){
      int row = mi*16 + lr;
      af[mi] = lds_bf8(&aLds[(row*256 + ks*32 + g*8) ^ ((row&7)<<3)]);
    }
    #pragma unroll
    for(int nj=0;nj<3;++nj)
      #pragma unroll
      for(int mi=0;mi<4;++mi) acc[mi][nj] = MFMA16(af[mi], bfr[nj], acc[mi][nj]);
  }
  #pragma unroll
  for(int nj=0;nj<3;++nj){
    int col = w*48 + nj*16 + lr;
    float bb = b_out[col];
    #pragma unroll
    for(int mi=0;mi<4;++mi)
      #pragma unroll
      for(int i=0;i<4;++i){
        int row = mi*16 + g*4 + i;
        out[(size_t)(m0+row)*192 + col] = acc[mi][nj][i] + bb;
      }
  }
}

extern "C" void kernel_launch(void* const* d_in, const int* in_sizes, int n_in,
                              void* d_out, int out_size, void* d_ws, size_t ws_size,
                              hipStream_t stream)
{
  const float* x  = (const float*)d_in[0];
  const float* Wq = (const float*)d_in[1];
  const float* Wk = (const float*)d_in[2];
  const float* Wv = (const float*)d_in[3];
  const float* Wl = (const float*)d_in[4];
  const float* bl = (const float*)d_in[5];
  const float* Wo = (const float*)d_in[6];
  const float* bo = (const float*)d_in[7];
  float* out = (float*)d_out;
  char* ws = (char*)d_ws;
  ushort_t* attnout = (ushort_t*)(ws);                 // 51.4 MB
  ushort_t* xwin    = (ushort_t*)(ws + 51380224);      // 50.3 MB
  ushort_t* locl    = (ushort_t*)(ws + 205520896);     // 51.4 MB
  ushort_t* qkvT    = (ushort_t*)(ws + 256901120);
  ushort_t* WcT     = (ushort_t*)(ws + 257196032);     // 884 KB
  ushort_t* woT     = (ushort_t*)(ws + 258375680);

  prep_kernel<<<14784, 256, 0, stream>>>(x, Wq, Wk, Wv, Wl, Wo,
                                         qkvT, woT, xwin, WcT);
  qkvattn_kernel<<<4096, 256, 0, stream>>>(xwin, qkvT, attnout);
  conv_kernel<<<784, 256, 0, stream>>>(xwin, WcT, bl, locl);
  outproj_kernel<<<1568, 256, 0, stream>>>(attnout, locl, woT, bo, out);
}

// Round 25
// 286.833 us; speedup vs baseline: 1.0612x; 1.0521x over previous
//
#include <hip/hip_runtime.h>

typedef unsigned short ushort_t;
typedef __bf16  bf16x8 __attribute__((ext_vector_type(8)));
typedef float   f32x4  __attribute__((ext_vector_type(4)));
typedef unsigned short u16x8 __attribute__((ext_vector_type(8)));

#define MFMA16(a,b,c) __builtin_amdgcn_mfma_f32_16x16x32_bf16((a),(b),(c),0,0,0)
#define WAITVM(N) asm volatile("s_waitcnt vmcnt(" #N ")" ::: "memory")
#define BARRIER() do{ __builtin_amdgcn_s_barrier(); asm volatile("" ::: "memory"); }while(0)

static __device__ __forceinline__ ushort_t f2bf(float f){
  __bf16 h = (__bf16)f;
  return __builtin_bit_cast(ushort_t, h);
}
static __device__ __forceinline__ float bf2f(ushort_t b){
  union{unsigned u; float f;} x; x.u = ((unsigned)b)<<16; return x.f;
}
static __device__ __forceinline__ bf16x8 ldg_bf8u(const ushort_t* p){
  u16x8 r = *(const u16x8*)p;
  return __builtin_bit_cast(bf16x8, r);
}
static __device__ __forceinline__ bf16x8 lds_bf8(const ushort_t* p){
  u16x8 r = *(const u16x8*)p;
  return __builtin_bit_cast(bf16x8, r);
}
// async global->LDS, 16B per lane; lds dst must be wave-uniform base + lane*16
static __device__ __forceinline__ void gload_lds16(const ushort_t* g, ushort_t* l){
  __builtin_amdgcn_global_load_lds(
      (const __attribute__((address_space(1))) void*)g,
      (__attribute__((address_space(3))) void*)l, 16, 0, 0);
}

// ---------------------------------------------------------------- prep
// qkvT[n(768)][k(192)]
// woT[n(192)][k(256)]
// xwin: [win(2048)][row(64)][192] bf16, rows>=49 zeroed, chunk-swizzle baked
// WcT:  composed conv weights, [tap(9)][ks(6)][col(256)][sl(4)][j(8)],
//       XOR-swizzle baked; W'[tap][c][o] = sum_k Wv[c][k]*Wl[tap][k][o]
__global__ __launch_bounds__(256) void prep_kernel(
    const float* __restrict__ x,
    const float* __restrict__ Wq, const float* __restrict__ Wk,
    const float* __restrict__ Wv, const float* __restrict__ Wl,
    const float* __restrict__ Wo,
    ushort_t* __restrict__ qkvT, ushort_t* __restrict__ woT,
    ushort_t* __restrict__ xwin, ushort_t* __restrict__ WcT)
{
  int idx = blockIdx.x*256 + threadIdx.x;
  if(idx < 147456){
    int n = idx/192, kk = idx%192;
    const float* W = (n < 256) ? Wq : ((n < 512) ? Wk : Wv);
    qkvT[idx] = f2bf(W[kk*256 + (n & 255)]);
  } else if(idx < 196608){
    int t3 = idx - 147456;
    int col = t3/256, kk = t3%256;
    woT[t3] = f2bf(Wo[kk*192 + col]);
  } else if(idx < 3342336){
    int c = idx - 196608;               // xwin chunk id, 2048*1536
    int win = c/1536, t = c%1536;
    int row = t/24, cp = t%24;
    u16x8 o = {0,0,0,0,0,0,0,0};
    if(row < 49){
      int b = win>>6, rem = win&63, wy = rem>>3, wx = rem&7;
      size_t base = (size_t)b*3136 + wy*392 + wx*7;
      int sc = cp ^ (row&7);
      const float* src = x + (base + (row/7)*56 + (row%7))*192 + sc*8;
      float4 f0 = *(const float4*)src;
      float4 f1 = *(const float4*)(src+4);
      o[0]=f2bf(f0.x); o[1]=f2bf(f0.y); o[2]=f2bf(f0.z); o[3]=f2bf(f0.w);
      o[4]=f2bf(f1.x); o[5]=f2bf(f1.y); o[6]=f2bf(f1.z); o[7]=f2bf(f1.w);
    }
    *(u16x8*)&xwin[(size_t)c*8] = o;
  } else if(idx < 3784704){
    // compose: one output element per thread; lanes on o (coalesced Wl)
    int t = idx - 3342336;
    int o = t & 255;
    int tc = t >> 8;                    // 0..1727, block-uniform
    int tap = tc / 192, c = tc % 192;
    const float* wlp = Wl + (size_t)tap*65536 + o;
    const float* wvp = Wv + (size_t)c*256;
    float acc = 0.f;
    #pragma unroll 8
    for(int k=0;k<256;++k)
      acc += wvp[k] * wlp[(size_t)k*256];
    int ks = c>>5, r = c&31, grp = r>>3, j = r&7;
    int sl = grp ^ ((o>>1)&3);
    WcT[((size_t)tap*6 + ks)*8192 + o*32 + sl*8 + j] = f2bf(acc);
  }
}

// ---------------------------------------------------------------- fused qkv + attention
// block = 256 thr (4 waves) = one window x 4 heads; grid 4096 (2 blocks/window).
// LDS 76 KB -> 2 blocks/CU = 256 VGPR budget; single 3-way interleaved q/k/v
// GEMM; phase 1 = pure linear DMA from pre-swizzled xwin. [measured ~105 us;
// r23/r24 LDS-overlay variants both regressed -- keep this form]
__global__ __launch_bounds__(256,2) void qkvattn_kernel(
    const ushort_t* __restrict__ xwin, const ushort_t* __restrict__ WT,
    ushort_t* __restrict__ attnout)
{
  // elems: xLds [0,12288) = 64x192 ; qk 12288 + w*4608 (q 64x36, k 64x36)
  //        vT 30720 + w*2048 (32x64) ; total 38912 elems = 76 KB
  __shared__ ushort_t lds[38912];
  ushort_t* xLds = lds;
  const int tid = threadIdx.x;
  const int w = tid>>6, l = tid&63, lr = l&15, g = l>>4;
  const int bid = blockIdx.x;
  const int win = bid>>1, head = (bid&1)*4 + w;
  const int b = win>>6, rem = win&63, wy = rem>>3, wx = rem&7;
  const size_t base = (size_t)b*3136 + wy*7*56 + wx*7;

  // ---- phase 1: pure linear DMA stage of pre-swizzled window x
  {
    const ushort_t* xsrc = xwin + (size_t)win*12288;
    #pragma unroll
    for(int r=0;r<6;++r)
      gload_lds16(xsrc + (size_t)(tid + r*256)*8,
                  xLds + (size_t)(r*256 + w*64)*8);
  }
  __syncthreads();   // drains vmcnt -> xLds valid

  ushort_t* qkBase = lds + 12288 + w*4608;   // q at +0, k at +2304
  ushort_t* vT     = lds + 30720 + w*2048;
  const ushort_t* Wq_ = WT + (size_t)(head*32)*192;
  const ushort_t* Wk_ = WT + (size_t)(256 + head*32)*192;
  const ushort_t* Wv_ = WT + (size_t)(512 + head*32)*192;

  // ---- single 3-way interleaved q,k,v GEMM (shared A-fragments)
  {
    f32x4 aq[4][2], ak[4][2], av[4][2];
    #pragma unroll
    for(int mi=0;mi<4;++mi)
      #pragma unroll
      for(int nj=0;nj<2;++nj){
        f32x4 z={0.f,0.f,0.f,0.f};
        aq[mi][nj]=z; ak[mi][nj]=z; av[mi][nj]=z;
      }
    #pragma unroll
    for(int ks=0; ks<6; ++ks){
      bf16x8 af[4];
      #pragma unroll
      for(int mi=0;mi<4;++mi){
        int row = mi*16 + lr;
        af[mi] = lds_bf8(&xLds[(row*192 + ks*32 + g*8) ^ ((row&7)<<3)]);
      }
      bf16x8 bq[2], bk[2], bv[2];
      #pragma unroll
      for(int nj=0;nj<2;++nj){
        size_t off = (size_t)(nj*16+lr)*192 + ks*32 + g*8;
        bq[nj] = ldg_bf8u(Wq_ + off);
        bk[nj] = ldg_bf8u(Wk_ + off);
        bv[nj] = ldg_bf8u(Wv_ + off);
      }
      #pragma unroll
      for(int nj=0;nj<2;++nj)
        #pragma unroll
        for(int mi=0;mi<4;++mi){
          aq[mi][nj] = MFMA16(af[mi], bq[nj], aq[mi][nj]);
          ak[mi][nj] = MFMA16(af[mi], bk[nj], ak[mi][nj]);
          av[mi][nj] = MFMA16(af[mi], bv[nj], av[mi][nj]);
        }
    }
    // q/k -> wave-private padded LDS [64][36]; v -> vT (wave-private only)
    #pragma unroll
    for(int mi=0;mi<4;++mi)
      #pragma unroll
      for(int nj=0;nj<2;++nj)
        #pragma unroll
        for(int i=0;i<4;++i){
          int row = mi*16 + g*4 + i, col = nj*16 + lr;
          qkBase[row*36 + col]        = f2bf(aq[mi][nj][i]);
          qkBase[2304 + row*36 + col] = f2bf(ak[mi][nj][i]);
          vT[(col*64 + row) ^ ((col&7)<<3)] = f2bf(av[mi][nj][i]);
        }
  }

  // ---- phase 3: QK^T
  f32x4 dot[4][4];
  #pragma unroll
  for(int mi=0;mi<4;++mi)
    #pragma unroll
    for(int nj=0;nj<4;++nj){ f32x4 z={0.f,0.f,0.f,0.f}; dot[mi][nj]=z; }
  bf16x8 qf[4], kf[4];
  #pragma unroll
  for(int t=0;t<4;++t){
    qf[t] = lds_bf8(&qkBase[(t*16+lr)*36 + g*8]);
    kf[t] = lds_bf8(&qkBase[2304 + (t*16+lr)*36 + g*8]);
  }
  #pragma unroll
  for(int mi=0;mi<4;++mi)
    #pragma unroll
    for(int nj=0;nj<4;++nj)
      dot[mi][nj] = MFMA16(qf[mi], kf[nj], dot[mi][nj]);

  // maxless softmax: P = exp2(S*sc), masked; no cross-lane ops.
  const float sc = 0.17677669529663687f * 1.4426950408889634f;
  ushort_t* pl = qkBase;   // P [64][64] reuses q/k region (frags in regs)
  #pragma unroll
  for(int mi=0;mi<4;++mi)
    #pragma unroll
    for(int nj=0;nj<4;++nj){
      int col = nj*16 + lr;
      #pragma unroll
      for(int i=0;i<4;++i){
        float e = (col < 49) ? exp2f(dot[mi][nj][i]*sc) : 0.f;
        int row = mi*16 + g*4 + i;
        pl[(row*64 + col) ^ ((row&7)<<3)] = f2bf(e);
      }
    }

  // PV + row-sum via P @ ones (lane-aligned with o's D-layout)
  u16x8 ones_u = {0x3f80,0x3f80,0x3f80,0x3f80,0x3f80,0x3f80,0x3f80,0x3f80};
  bf16x8 ones8 = __builtin_bit_cast(bf16x8, ones_u);
  f32x4 o[4][2], rsum[4];
  #pragma unroll
  for(int mi=0;mi<4;++mi){
    f32x4 z={0.f,0.f,0.f,0.f};
    o[mi][0]=z; o[mi][1]=z; rsum[mi]=z;
  }
  #pragma unroll
  for(int ks=0;ks<2;++ks){
    bf16x8 pa[4];
    #pragma unroll
    for(int mi=0;mi<4;++mi){
      int row = mi*16 + lr;
      pa[mi] = lds_bf8(&pl[(row*64 + ks*32 + g*8) ^ ((row&7)<<3)]);
    }
    #pragma unroll
    for(int nj=0;nj<2;++nj){
      int d = nj*16 + lr;
      bf16x8 vb = lds_bf8(&vT[(d*64 + ks*32 + g*8) ^ ((d&7)<<3)]);
      #pragma unroll
      for(int mi=0;mi<4;++mi) o[mi][nj] = MFMA16(pa[mi], vb, o[mi][nj]);
    }
    #pragma unroll
    for(int mi=0;mi<4;++mi) rsum[mi] = MFMA16(pa[mi], ones8, rsum[mi]);
  }
  #pragma unroll
  for(int mi=0;mi<4;++mi){
    #pragma unroll
    for(int i=0;i<4;++i){
      int row = mi*16 + g*4 + i;
      if(row < 49){
        size_t pix = base + (row/7)*56 + (row%7);
        float inv = 1.0f / rsum[mi][i];
        #pragma unroll
        for(int nj=0;nj<2;++nj)
          attnout[pix*256 + head*32 + nj*16 + lr] = f2bf(o[mi][nj][i] * inv);
      }
    }
  }
}

// ---------------------------------------------------------------- 3x3 conv (composed weights, A from xwin; measured ~114.5 us)
// local = x (*) W'  with K_total = 1728: 54 phases. A gathered from the
// window-blocked xwin via per-thread precomputed offsets. B = WcT.
__global__ __launch_bounds__(256,2) void conv_kernel(
    const ushort_t* __restrict__ xwin, const ushort_t* __restrict__ WcT,
    const float* __restrict__ b_local, ushort_t* __restrict__ local_out)
{
  __shared__ ushort_t aBuf[2][256*32];   // 2 x 16 KB
  __shared__ ushort_t bBuf[3][256*32];   // 3 x 16 KB
  const int bid = blockIdx.x;
  const int tile = (bid & 7) * 98 + (bid >> 3);   // XCD-contiguous (784 = 8*98)
  const int p0 = tile * 128;
  const int tid = threadIdx.x;
  const int l = tid&63, w=tid>>6, wm=w>>1, wn=w&1, lr=l&15, g=l>>4;

  unsigned maskbits[4];
  int pxloc[4];
  #pragma unroll
  for(int mi=0;mi<4;++mi){
    int p = p0 + wm*64 + mi*16 + lr;
    int rem = p % 3136;
    int y = rem/56, x = rem%56;
    unsigned mb = 0;
    #pragma unroll
    for(int tap=0;tap<9;++tap){
      int dy = tap/3 - 1, dx = tap%3 - 1;
      if(((unsigned)(y+dy) < 56u) && ((unsigned)(x+dx) < 56u)) mb |= (1u<<tap);
    }
    maskbits[mi] = mb;
    pxloc[mi] = wm*64 + mi*16 + lr + 64;
  }

  // one-time gather precompute for stageA: pixel -> (win,row) in xwin
  unsigned aBase[4]; int aR7[4], aWant[4];
  #pragma unroll
  for(int r=0;r<4;++r){
    int c = tid + r*256;
    int px = c>>2, sl = c&3;
    int px_abs = p0 - 64 + px;
    px_abs = min(max(px_abs, 0), 100351);
    int b2 = px_abs/3136, rem2 = px_abs%3136;
    int y2 = rem2/56, x2 = rem2%56;
    int win2 = b2*64 + (y2/7)*8 + (x2/7);
    int row2 = (y2%7)*7 + (x2%7);
    aBase[r] = (unsigned)win2*12288u + (unsigned)row2*192u;
    aR7[r]   = row2 & 7;
    aWant[r] = sl ^ ((px>>1)&3);
  }

  auto stageA = [&](int ks, ushort_t* dst){
    #pragma unroll
    for(int r=0;r<4;++r){
      int cp = (ks*4 + aWant[r]) ^ aR7[r];
      gload_lds16(xwin + aBase[r] + cp*8,
                  dst + (size_t)(r*256 + w*64)*8);
    }
  };
  auto stageB = [&](int ks, int tap, ushort_t* dst){
    const ushort_t* src = WcT + ((size_t)tap*6 + ks)*8192;
    #pragma unroll
    for(int r=0;r<4;++r){
      gload_lds16(src + (size_t)(tid + r*256)*8,
                  dst + (size_t)(r*256 + w*64)*8);
    }
  };

  f32x4 acc[4][8];
  #pragma unroll
  for(int mi=0;mi<4;++mi)
    #pragma unroll
    for(int nj=0;nj<8;++nj){ f32x4 z={0.f,0.f,0.f,0.f}; acc[mi][nj]=z; }

  auto compute = [&](int tap, const ushort_t* aL, const ushort_t* bL){
    int shift = (tap/3 - 1)*56 + (tap%3 - 1);
    bf16x8 af[4];
    #pragma unroll
    for(int mi=0;mi<4;++mi){
      int px = pxloc[mi] + shift;
      int sl = g ^ ((px>>1)&3);
      u16x8 rv = *(const u16x8*)&aL[px*32 + sl*8];
      if(!((maskbits[mi]>>tap)&1)){ u16x8 z={0,0,0,0,0,0,0,0}; rv=z; }
      af[mi] = __builtin_bit_cast(bf16x8, rv);
    }
    __builtin_amdgcn_s_setprio(1);
    #pragma unroll
    for(int nj=0;nj<8;++nj){
      int col = wn*128 + nj*16 + lr;
      int slb = g ^ ((col>>1)&3);
      bf16x8 bfr = lds_bf8(&bL[col*32 + slb*8]);
      #pragma unroll
      for(int mi=0;mi<4;++mi) acc[mi][nj] = MFMA16(af[mi], bfr, acc[mi][nj]);
    }
    __builtin_amdgcn_s_setprio(0);
  };

  stageA(0, aBuf[0]);
  stageB(0, 0, bBuf[0]);
  stageB(0, 1, bBuf[1]);

  for(int ks=0; ks<5; ++ks){
    #pragma unroll
    for(int tap=0; tap<9; ++tap){
      if(tap==1) WAITVM(8); else WAITVM(4);
      BARRIER();
      if(tap==0) stageA(ks+1, aBuf[(ks+1)&1]);
      stageB(ks + (tap+2)/9, (tap+2)%9, bBuf[(tap+2)%3]);
      compute(tap, aBuf[ks&1], bBuf[tap%3]);
    }
  }
  #pragma unroll
  for(int tap=0; tap<9; ++tap){
    if(tap==8) WAITVM(0); else WAITVM(4);
    BARRIER();
    if(tap<7) stageB(5, tap+2, bBuf[(tap+2)%3]);
    compute(tap, aBuf[1], bBuf[tap%3]);
  }

  #pragma unroll
  for(int nj=0;nj<8;++nj){
    int col = wn*128 + nj*16 + lr;
    float bb = b_local[col];
    #pragma unroll
    for(int mi=0;mi<4;++mi)
      #pragma unroll
      for(int i=0;i<4;++i){
        int p = p0 + wm*64 + mi*16 + g*4 + i;
        local_out[(size_t)p*256 + col] = f2bf(acc[mi][nj][i] + bb);
      }
  }
}

// ---------------------------------------------------------------- out proj
// out[100352,192] = (attnout+locl)[100352,256] @ Wout[256,192] + b_out
// 64px x 192col blocks, 4 waves (1m x 4n), wave 64x48; add fused in staging.
__global__ __launch_bounds__(256,4) void outproj_kernel(
    const ushort_t* __restrict__ attnout, const ushort_t* __restrict__ locl,
    const ushort_t* __restrict__ WoT, const float* __restrict__ b_out,
    float* __restrict__ out)
{
  __shared__ ushort_t aLds[64*256];   // 32 KB
  const int m0 = blockIdx.x * 64;
  const int tid = threadIdx.x;
  const int l = tid&63, w = tid>>6, lr=l&15, g=l>>4;
  #pragma unroll
  for(int r=0;r<8;++r){
    int c = tid + r*256;           // 2048 chunks = 64 rows x 32
    int row = c>>5, cc = c&31;
    size_t off = (size_t)(m0+row)*256 + cc*8;
    u16x8 a = *(const u16x8*)(attnout + off);
    u16x8 b2 = *(const u16x8*)(locl + off);
    u16x8 o;
    #pragma unroll
    for(int j=0;j<8;++j) o[j] = f2bf(bf2f(a[j]) + bf2f(b2[j]));
    *(u16x8*)&aLds[(row*256 + cc*8) ^ ((row&7)<<3)] = o;
  }
  __syncthreads();

  const ushort_t* Wbase = WoT + (size_t)(w*48)*256;
  f32x4 acc[4][3];
  #pragma unroll
  for(int mi=0;mi<4;++mi)
    #pragma unroll
    for(int nj=0;nj<3;++nj){ f32x4 z={0.f,0.f,0.f,0.f}; acc[mi][nj]=z; }

  #pragma unroll
  for(int ks=0;ks<8;++ks){
    bf16x8 bfr[3];
    #pragma unroll
    for(int nj=0;nj<3;++nj)
      bfr[nj] = ldg_bf8u(Wbase + (size_t)(nj*16+lr)*256 + ks*32 + g*8);
    bf16x8 af[4];
    #pragma unroll
    for(int mi=0;mi<4;++mi){
      int row = mi*16 + lr;
      af[mi] = lds_bf8(&aLds[(row*256 + ks*32 + g*8) ^ ((row&7)<<3)]);
    }
    #pragma unroll
    for(int nj=0;nj<3;++nj)
      #pragma unroll
      for(int mi=0;mi<4;++mi) acc[mi][nj] = MFMA16(af[mi], bfr[nj], acc[mi][nj]);
  }
  #pragma unroll
  for(int nj=0;nj<3;++nj){
    int col = w*48 + nj*16 + lr;
    float bb = b_out[col];
    #pragma unroll
    for(int mi=0;mi<4;++mi)
      #pragma unroll
      for(int i=0;i<4;++i){
        int row = mi*16 + g*4 + i;
        out[(size_t)(m0+row)*192 + col] = acc[mi][nj][i] + bb;
      }
  }
}

extern "C" void kernel_launch(void* const* d_in, const int* in_sizes, int n_in,
                              void* d_out, int out_size, void* d_ws, size_t ws_size,
                              hipStream_t stream)
{
  const float* x  = (const float*)d_in[0];
  const float* Wq = (const float*)d_in[1];
  const float* Wk = (const float*)d_in[2];
  const float* Wv = (const float*)d_in[3];
  const float* Wl = (const float*)d_in[4];
  const float* bl = (const float*)d_in[5];
  const float* Wo = (const float*)d_in[6];
  const float* bo = (const float*)d_in[7];
  float* out = (float*)d_out;
  char* ws = (char*)d_ws;
  ushort_t* attnout = (ushort_t*)(ws);                 // 51.4 MB
  ushort_t* xwin    = (ushort_t*)(ws + 51380224);      // 50.3 MB
  ushort_t* locl    = (ushort_t*)(ws + 205520896);     // 51.4 MB
  ushort_t* qkvT    = (ushort_t*)(ws + 256901120);
  ushort_t* WcT     = (ushort_t*)(ws + 257196032);     // 884 KB
  ushort_t* woT     = (ushort_t*)(ws + 258375680);

  prep_kernel<<<14784, 256, 0, stream>>>(x, Wq, Wk, Wv, Wl, Wo,
                                         qkvT, woT, xwin, WcT);
  qkvattn_kernel<<<4096, 256, 0, stream>>>(xwin, qkvT, attnout);
  conv_kernel<<<784, 256, 0, stream>>>(xwin, WcT, bl, locl);
  outproj_kernel<<<1568, 256, 0, stream>>>(attnout, locl, woT, bo, out);
}